// Round 8
// baseline (95.193 us; speedup 1.0000x reference)
//
#include <hip/hip_runtime.h>
#include <hip/hip_bf16.h>
#include <cstdint>

// CTC forward loss (keras ctc_batch_cost), B=64 T=1024 L=128 V=512.
// Two-phase:
//   K1 (gather, 4096 blocks): y_pred rows -> LDS -> gather 129 probs/(b,t),
//      pre-add EPSF, bf16-pack label pairs -> pairs[B][T][64] u32 in d_ws;
//      blank+EPSF as f32 -> blk[B][T]. Waves independent, no barriers.
//   K2 (scan, 64 blocks x 1 wave): probability-domain scaled forward scan,
//      NO LDS, NO barriers, NO producer wave. 16-deep register prefetch of
//      pair words (1 coalesced global_load_dword/step, imm offsets), blanks
//      via float4 every 4 steps. DPP for cross-lane. Renorm every 4 steps
//      (exact pow2 bookkeeping, deferred one period — r7's period-8 hit
//      denormal-flush troughs on rare low-prob stretches; period 4 + BIASE 90
//      restores r6's proven margins). t=0 folded into the uniform step via
//      pre-state a0 = (lane==0), so T = 32 iters x 32 steps, no peeling.
// Fallback to round-5 single kernel if ws too small.

#define CTC_B 64
#define CTC_T 1024
#define CTC_L 128
#define CTC_V 512
#define BLANK (CTC_V - 1)
#define EPSF 1e-7f
#define LN2F 0.69314718055994530942f
#define BIASE 90
#define K1ROWS 16

__device__ __forceinline__ void gld_lds16f(const float* g, float* l) {
    __builtin_amdgcn_global_load_lds(
        (const __attribute__((address_space(1))) unsigned int*)g,
        (__attribute__((address_space(3))) unsigned int*)l, 16, 0, 0);
}

template<int CTRL>
__device__ __forceinline__ float dpp_mov0(float v) {
    int r = __builtin_amdgcn_update_dpp(0, __float_as_int(v), CTRL, 0xf, 0xf, false);
    return __int_as_float(r);
}
template<int CTRL>
__device__ __forceinline__ float dpp_max(float v) {
    int r = __builtin_amdgcn_update_dpp(__float_as_int(v), __float_as_int(v),
                                        CTRL, 0xf, 0xf, false);
    return fmaxf(v, __int_as_float(r));
}
__device__ __forceinline__ uint32_t rne16(float x) {
    return (__float_as_uint(x) + 0x8000u) >> 16;
}

// ---------------- K1: gather + pack (eps pre-added) ----------------
__global__ __launch_bounds__(256, 1)
void ctc_gather(const int* __restrict__ y_true,
                const float* __restrict__ y_pred,
                uint32_t* __restrict__ pairs,
                float* __restrict__ blk) {
    __shared__ __align__(16) float rows[K1ROWS][CTC_V];   // 32 KB

    const int bid = blockIdx.x;
    const int b = bid >> 6;
    const int t0 = (bid & 63) * K1ROWS;
    const int w = threadIdx.x >> 6;
    const int lane = threadIdx.x & 63;
    const float* __restrict__ yb = y_pred + ((size_t)b * CTC_T + t0) * CTC_V;

    const int2 lp = *(const int2*)&y_true[b * CTC_L + 2 * lane];

#pragma unroll
    for (int r = 0; r < 4; ++r) {
        const int row = 4 * w + r;
        const float* g = yb + (size_t)row * CTC_V + lane * 4;
        gld_lds16f(g, &rows[row][0]);
        gld_lds16f(g + 256, &rows[row][256]);
    }
    asm volatile("s_waitcnt vmcnt(0)" ::: "memory");

#pragma unroll
    for (int r = 0; r < 4; ++r) {
        const int row = 4 * w + r;
        const float* rowp = &rows[row][0];
        const float c0 = rowp[lp.x] + EPSF;
        const float c1 = rowp[lp.y] + EPSF;
        const uint32_t pk = rne16(c0) | (rne16(c1) << 16);
        pairs[((size_t)b * CTC_T + t0 + row) * 64 + lane] = pk;
        if (lane == 0) blk[b * CTC_T + t0 + row] = rowp[BLANK] + EPSF;
    }
}

// ---------------- K2: single-wave register-pipelined scan ----------------
__global__ __launch_bounds__(64, 1)
void ctc_scan2(const int* __restrict__ y_true,
               const uint32_t* __restrict__ pairs,
               const float* __restrict__ blk,
               float* __restrict__ out) {
    const int b = blockIdx.x;
    const int lane = threadIdx.x;

    const uint32_t* pcur = pairs + (size_t)b * CTC_T * 64 + lane;
    const float* bcur = blk + (size_t)b * CTC_T;

    const int labA = y_true[b * CTC_L + 2 * lane];
    const int labB = y_true[b * CTC_L + 2 * lane + 1];
    const int labPrev = __shfl_up(labB, 1);
    const float msk1 = (labA != labPrev) ? 1.0f : 0.0f;
    const float msk3 = (labB != labA) ? 1.0f : 0.0f;

    // pre-state: virtual "alpha[-1]" delta; t=0 becomes a uniform step
    float a0 = (lane == 0) ? 1.0f : 0.0f;
    float a1 = 0.0f, a2 = 0.0f, a3 = 0.0f, a4 = 0.0f;
    float curScale = 1.0f;
    int curE = 0, Eacc = 0;

    // 16-slot pair ring + double-buffered blank quads
    uint32_t v0, v1, v2, v3, v4, v5, v6, v7, v8, v9, v10, v11, v12, v13, v14, v15;
    float4 bqA0, bqA1, bqA2, bqA3, bqB0, bqB1, bqB2, bqB3;

    // prologue: slots t=0..15, blanks t=0..31
    v0  = pcur[0 * 64];  v1  = pcur[1 * 64];  v2  = pcur[2 * 64];  v3  = pcur[3 * 64];
    v4  = pcur[4 * 64];  v5  = pcur[5 * 64];  v6  = pcur[6 * 64];  v7  = pcur[7 * 64];
    v8  = pcur[8 * 64];  v9  = pcur[9 * 64];  v10 = pcur[10 * 64]; v11 = pcur[11 * 64];
    v12 = pcur[12 * 64]; v13 = pcur[13 * 64]; v14 = pcur[14 * 64]; v15 = pcur[15 * 64];
    bqA0 = *(const float4*)(bcur + 0);  bqA1 = *(const float4*)(bcur + 4);
    bqA2 = *(const float4*)(bcur + 8);  bqA3 = *(const float4*)(bcur + 12);
    bqB0 = *(const float4*)(bcur + 16); bqB1 = *(const float4*)(bcur + 20);
    bqB2 = *(const float4*)(bcur + 24); bqB3 = *(const float4*)(bcur + 28);

#define STEP(vk, bv) do {                                                  \
        const float pb_ = (bv);                                            \
        const float pA_ = __uint_as_float((vk) << 16);                     \
        const float pB_ = __uint_as_float((vk) & 0xffff0000u);             \
        const float pm1_ = dpp_mov0<0x138>(a3); /* wave_shr:1, lane0->0 */ \
        const float n0_ = (a0 + pm1_) * pb_;                               \
        const float n1_ = fmaf(msk1, pm1_, a0 + a1) * pA_;                 \
        const float n2_ = (a1 + a2) * pb_;                                 \
        const float n3_ = fmaf(msk3, a1, a2 + a3) * pB_;                   \
        const float n4_ = (a3 + a4) * pb_;                                 \
        a0 = n0_; a1 = n1_; a2 = n2_; a3 = n3_; a4 = n4_;                  \
    } while (0)

#define DORN() do {                                                        \
        a0 *= curScale; a1 *= curScale; a2 *= curScale;                    \
        a3 *= curScale; a4 *= curScale;                                    \
        Eacc += curE;                                                      \
        float m_ = fmaxf(fmaxf(fmaxf(a0, a1), fmaxf(a2, a3)), a4);         \
        m_ = dpp_max<0x111>(m_);  /* row_shr:1  */                         \
        m_ = dpp_max<0x112>(m_);  /* row_shr:2  */                         \
        m_ = dpp_max<0x114>(m_);  /* row_shr:4  */                         \
        m_ = dpp_max<0x118>(m_);  /* row_shr:8  */                         \
        m_ = dpp_max<0x142>(m_);  /* row_bcast:15 */                       \
        m_ = dpp_max<0x143>(m_);  /* row_bcast:31 */                       \
        const int mb_ = __builtin_amdgcn_readlane(__float_as_int(m_), 63); \
        const int e_ = (mb_ >> 23) & 255;                                  \
        int k_ = 127 + BIASE + 127 - e_;                                   \
        k_ = k_ > 254 ? 254 : (k_ < 1 ? 1 : k_);                           \
        curScale = __int_as_float((unsigned)k_ << 23);                     \
        curE = 127 - k_;                                                   \
    } while (0)

#define RELOAD(K) v##K = pcur[(16 + K) * 64]

    for (int ob = 0; ob < 32; ++ob) {
        // -------- phase A: t = 32*ob .. +15, blanks bqA --------
        STEP(v0,  bqA0.x); RELOAD(0);
        STEP(v1,  bqA0.y); RELOAD(1);
        STEP(v2,  bqA0.z); RELOAD(2);
        STEP(v3,  bqA0.w); RELOAD(3);  bqA0 = *(const float4*)(bcur + 32); DORN();
        STEP(v4,  bqA1.x); RELOAD(4);
        STEP(v5,  bqA1.y); RELOAD(5);
        STEP(v6,  bqA1.z); RELOAD(6);
        STEP(v7,  bqA1.w); RELOAD(7);  bqA1 = *(const float4*)(bcur + 36); DORN();
        STEP(v8,  bqA2.x); RELOAD(8);
        STEP(v9,  bqA2.y); RELOAD(9);
        STEP(v10, bqA2.z); RELOAD(10);
        STEP(v11, bqA2.w); RELOAD(11); bqA2 = *(const float4*)(bcur + 40); DORN();
        STEP(v12, bqA3.x); RELOAD(12);
        STEP(v13, bqA3.y); RELOAD(13);
        STEP(v14, bqA3.z); RELOAD(14);
        STEP(v15, bqA3.w); RELOAD(15); bqA3 = *(const float4*)(bcur + 44); DORN();
        pcur += 16 * 64;
        // -------- phase B: t = 32*ob+16 .. +31, blanks bqB --------
        STEP(v0,  bqB0.x); RELOAD(0);
        STEP(v1,  bqB0.y); RELOAD(1);
        STEP(v2,  bqB0.z); RELOAD(2);
        STEP(v3,  bqB0.w); RELOAD(3);  bqB0 = *(const float4*)(bcur + 48); DORN();
        STEP(v4,  bqB1.x); RELOAD(4);
        STEP(v5,  bqB1.y); RELOAD(5);
        STEP(v6,  bqB1.z); RELOAD(6);
        STEP(v7,  bqB1.w); RELOAD(7);  bqB1 = *(const float4*)(bcur + 52); DORN();
        STEP(v8,  bqB2.x); RELOAD(8);
        STEP(v9,  bqB2.y); RELOAD(9);
        STEP(v10, bqB2.z); RELOAD(10);
        STEP(v11, bqB2.w); RELOAD(11); bqB2 = *(const float4*)(bcur + 56); DORN();
        STEP(v12, bqB3.x); RELOAD(12);
        STEP(v13, bqB3.y); RELOAD(13);
        STEP(v14, bqB3.z); RELOAD(14);
        STEP(v15, bqB3.w); RELOAD(15); bqB3 = *(const float4*)(bcur + 60); DORN();
        pcur += 16 * 64;
        bcur += 32;
    }

    if (lane == 63) {
        out[b] = -(logf(a3 + a4) + (float)Eacc * LN2F);
    }
#undef RELOAD
#undef DORN
#undef STEP
}

// ---------------- fallback: round-5 single kernel ----------------
#define F_CHUNK 16
#define F_NBUF  4
#define F_NCH   (CTC_T / F_CHUNK)

__global__ __launch_bounds__(256, 1)
void ctc_fwd_stream(const int* __restrict__ y_true,
                    const float* __restrict__ y_pred,
                    float* __restrict__ out) {
    __shared__ __align__(16) float rows[F_NBUF][F_CHUNK][CTC_V];
    const int b = blockIdx.x;
    const int tid = threadIdx.x;
    const int wave = tid >> 6;
    const int lane = tid & 63;
    const float* __restrict__ yb = y_pred + (size_t)b * CTC_T * CTC_V;

    if (wave != 0) {
        const int w = wave - 1;
#define FISSUE(c_) do {                                                    \
            const int t0_ = (c_) * F_CHUNK;                                \
            float* bufb_ = &rows[(c_) & (F_NBUF - 1)][0][0];               \
            for (int l_ = w; l_ < F_CHUNK; l_ += 3) {                      \
                const float* g_ = yb + (size_t)(t0_ + l_) * CTC_V + lane * 4; \
                float* d_ = bufb_ + l_ * CTC_V;                            \
                gld_lds16f(g_, d_);                                        \
                gld_lds16f(g_ + 256, d_ + 256);                            \
            }                                                              \
        } while (0)
        FISSUE(0); FISSUE(1); FISSUE(2);
        if (w == 0) asm volatile("s_waitcnt vmcnt(24)" ::: "memory");
        else        asm volatile("s_waitcnt vmcnt(20)" ::: "memory");
        __builtin_amdgcn_s_barrier();
        __builtin_amdgcn_sched_barrier(0);
        for (int c = 0; c < F_NCH; ++c) {
            if (c + 3 < F_NCH) FISSUE(c + 3);
            if (c <= F_NCH - 4) {
                if (w == 0) asm volatile("s_waitcnt vmcnt(24)" ::: "memory");
                else        asm volatile("s_waitcnt vmcnt(20)" ::: "memory");
            } else if (c == F_NCH - 3) {
                if (w == 0) asm volatile("s_waitcnt vmcnt(12)" ::: "memory");
                else        asm volatile("s_waitcnt vmcnt(10)" ::: "memory");
            } else if (c == F_NCH - 2) {
                asm volatile("s_waitcnt vmcnt(0)" ::: "memory");
            }
            __builtin_amdgcn_s_barrier();
            __builtin_amdgcn_sched_barrier(0);
        }
        return;
#undef FISSUE
    }

    const int labA = y_true[b * CTC_L + 2 * lane];
    const int labB = y_true[b * CTC_L + 2 * lane + 1];
    const int labPrev = __shfl_up(labB, 1);
    const float msk1 = (labA != labPrev) ? 1.0f : 0.0f;
    const float msk3 = (labB != labA) ? 1.0f : 0.0f;

    float a0 = 0.0f, a1 = 0.0f, a2 = 0.0f, a3 = 0.0f, a4 = 0.0f;
    float curScale = 1.0f;
    int curE = 0, Eacc = 0;
    float pAA0, pBA0, blA0, pAA1, pBA1, blA1, pAA2, pBA2, blA2, pAA3, pBA3, blA3;
    float pAB0, pBB0, blB0, pAB1, pBB1, blB1, pAB2, pBB2, blB2, pAB3, pBB3, blB3;
    float pAC0, pBC0, blC0, pAC1, pBC1, blC1, pAC2, pBC2, blC2, pAC3, pBC3, blC3;

#define FLOADG(S, l_) do {                                                 \
        const float* r0_ = bufc + ((l_) + 0) * CTC_V;                      \
        const float* r1_ = bufc + ((l_) + 1) * CTC_V;                      \
        const float* r2_ = bufc + ((l_) + 2) * CTC_V;                      \
        const float* r3_ = bufc + ((l_) + 3) * CTC_V;                      \
        pA##S##0 = r0_[labA]; pB##S##0 = r0_[labB]; bl##S##0 = r0_[BLANK]; \
        pA##S##1 = r1_[labA]; pB##S##1 = r1_[labB]; bl##S##1 = r1_[BLANK]; \
        pA##S##2 = r2_[labA]; pB##S##2 = r2_[labB]; bl##S##2 = r2_[BLANK]; \
        pA##S##3 = r3_[labA]; pB##S##3 = r3_[labB]; bl##S##3 = r3_[BLANK]; \
    } while (0)
#define FDOSTEP(S, k) do {                                                 \
        const float pb_ = bl##S##k + EPSF;                                 \
        const float pA_ = pA##S##k + EPSF;                                 \
        const float pB_ = pB##S##k + EPSF;                                 \
        const float pm1_ = dpp_mov0<0x138>(a3);                            \
        const float n0_ = (a0 + pm1_) * pb_;                               \
        const float n1_ = fmaf(msk1, pm1_, a0 + a1) * pA_;                 \
        const float n2_ = (a1 + a2) * pb_;                                 \
        const float n3_ = fmaf(msk3, a1, a2 + a3) * pB_;                   \
        const float n4_ = (a3 + a4) * pb_;                                 \
        a0 = n0_; a1 = n1_; a2 = n2_; a3 = n3_; a4 = n4_;                  \
    } while (0)
#define FDORN() do {                                                       \
        a0 *= curScale; a1 *= curScale; a2 *= curScale;                    \
        a3 *= curScale; a4 *= curScale;                                    \
        Eacc += curE;                                                      \
        float m_ = fmaxf(fmaxf(fmaxf(a0, a1), fmaxf(a2, a3)), a4);         \
        m_ = dpp_max<0x111>(m_); m_ = dpp_max<0x112>(m_);                  \
        m_ = dpp_max<0x114>(m_); m_ = dpp_max<0x118>(m_);                  \
        m_ = dpp_max<0x142>(m_); m_ = dpp_max<0x143>(m_);                  \
        const int mb_ = __builtin_amdgcn_readlane(__float_as_int(m_), 63); \
        const int e_ = (mb_ >> 23) & 255;                                  \
        int k_ = 127 + BIASE + 127 - e_;                                   \
        k_ = k_ > 254 ? 254 : (k_ < 1 ? 1 : k_);                           \
        curScale = __int_as_float((unsigned)k_ << 23);                     \
        curE = 127 - k_;                                                   \
    } while (0)
#define FPROC4_RN(S) do {                                                  \
        FDOSTEP(S, 0); FDORN();                                            \
        FDOSTEP(S, 1); FDOSTEP(S, 2); FDOSTEP(S, 3);                       \
    } while (0)

    __builtin_amdgcn_s_barrier();
    __builtin_amdgcn_sched_barrier(0);
    for (int c = 0; c < F_NCH; ++c) {
        const float* bufc = &rows[c & (F_NBUF - 1)][0][0];
        if (c == 0) {
            const float pb0 = bufc[BLANK] + EPSF;
            const float plA = bufc[labA] + EPSF;
            FLOADG(A, 0); FLOADG(B, 4); FLOADG(C, 8);
            a0 = (lane == 0) ? pb0 : 0.0f;
            a1 = (lane == 0) ? plA : 0.0f;
            FDOSTEP(A, 1); FDOSTEP(A, 2); FDOSTEP(A, 3);
            FLOADG(A, 12);
            FPROC4_RN(B); FPROC4_RN(C); FPROC4_RN(A);
        } else {
            FLOADG(A, 0); FLOADG(B, 4); FLOADG(C, 8);
            FPROC4_RN(A); FLOADG(A, 12);
            FPROC4_RN(B); FPROC4_RN(C); FPROC4_RN(A);
        }
        __builtin_amdgcn_s_barrier();
        __builtin_amdgcn_sched_barrier(0);
    }
    if (lane == 63) {
        out[b] = -(logf(a3 + a4) + (float)Eacc * LN2F);
    }
#undef FPROC4_RN
#undef FDORN
#undef FDOSTEP
#undef FLOADG
}

extern "C" void kernel_launch(void* const* d_in, const int* in_sizes, int n_in,
                              void* d_out, int out_size, void* d_ws, size_t ws_size,
                              hipStream_t stream) {
    (void)in_sizes; (void)n_in; (void)out_size;
    const int* y_true = (const int*)d_in[0];     // [B, L] int32
    const float* y_pred = (const float*)d_in[1]; // [B, T, V] float32
    float* out = (float*)d_out;                  // [B, 1] float32

    const size_t pairsBytes = (size_t)CTC_B * CTC_T * 64 * sizeof(uint32_t); // 16.78 MB
    const size_t blkBytes = (size_t)CTC_B * CTC_T * sizeof(float);           // 256 KB
    const size_t need = pairsBytes + blkBytes + 65536;                       // + overread slack
    if (ws_size >= need) {
        uint32_t* pairs = (uint32_t*)d_ws;
        float* blk = (float*)((char*)d_ws + pairsBytes);
        ctc_gather<<<CTC_B * (CTC_T / K1ROWS), 256, 0, stream>>>(y_true, y_pred, pairs, blk);
        ctc_scan2<<<CTC_B, 64, 0, stream>>>(y_true, pairs, blk, out);
    } else {
        ctc_fwd_stream<<<CTC_B, 256, 0, stream>>>(y_true, y_pred, out);
    }
}

// Round 9
// 94.262 us; speedup vs baseline: 1.0099x; 1.0099x over previous
//
#include <hip/hip_runtime.h>
#include <hip/hip_bf16.h>
#include <cstdint>

// CTC forward loss (keras ctc_batch_cost), B=64 T=1024 L=128 V=512.
// Two-phase:
//   K1 (gather, 4096 blocks): y_pred rows -> LDS -> gather 129 probs/(b,t),
//      pre-add EPSF, bf16-pack label pairs -> pairs[B][T][64] u32 in d_ws;
//      blank+EPSF as f32 -> blk[B][T]. Waves independent, no barriers.
//   K2 (scan, 64 blocks x 1 wave): probability-domain scaled forward scan,
//      NO LDS, NO barriers, NO producer wave. 16-deep register prefetch of
//      pair words (1 coalesced global_load_dword/step, imm offsets), blanks
//      via float4 every 4 steps. DPP for cross-lane. Renorm every 4 steps
//      (exact pow2 bookkeeping, deferred one period — r7's period-8 hit
//      denormal-flush troughs on rare low-prob stretches; period 4 + BIASE 90
//      restores r6's proven margins). t=0 folded into the uniform step via
//      pre-state a0 = (lane==0), so T = 32 iters x 32 steps, no peeling.
// Fallback to round-5 single kernel if ws too small.

#define CTC_B 64
#define CTC_T 1024
#define CTC_L 128
#define CTC_V 512
#define BLANK (CTC_V - 1)
#define EPSF 1e-7f
#define LN2F 0.69314718055994530942f
#define BIASE 90
#define K1ROWS 16

__device__ __forceinline__ void gld_lds16f(const float* g, float* l) {
    __builtin_amdgcn_global_load_lds(
        (const __attribute__((address_space(1))) unsigned int*)g,
        (__attribute__((address_space(3))) unsigned int*)l, 16, 0, 0);
}

template<int CTRL>
__device__ __forceinline__ float dpp_mov0(float v) {
    int r = __builtin_amdgcn_update_dpp(0, __float_as_int(v), CTRL, 0xf, 0xf, false);
    return __int_as_float(r);
}
template<int CTRL>
__device__ __forceinline__ float dpp_max(float v) {
    int r = __builtin_amdgcn_update_dpp(__float_as_int(v), __float_as_int(v),
                                        CTRL, 0xf, 0xf, false);
    return fmaxf(v, __int_as_float(r));
}
__device__ __forceinline__ uint32_t rne16(float x) {
    return (__float_as_uint(x) + 0x8000u) >> 16;
}

// ---------------- K1: gather + pack (eps pre-added) ----------------
__global__ __launch_bounds__(256, 1)
void ctc_gather(const int* __restrict__ y_true,
                const float* __restrict__ y_pred,
                uint32_t* __restrict__ pairs,
                float* __restrict__ blk) {
    __shared__ __align__(16) float rows[K1ROWS][CTC_V];   // 32 KB

    const int bid = blockIdx.x;
    const int b = bid >> 6;
    const int t0 = (bid & 63) * K1ROWS;
    const int w = threadIdx.x >> 6;
    const int lane = threadIdx.x & 63;
    const float* __restrict__ yb = y_pred + ((size_t)b * CTC_T + t0) * CTC_V;

    const int2 lp = *(const int2*)&y_true[b * CTC_L + 2 * lane];

#pragma unroll
    for (int r = 0; r < 4; ++r) {
        const int row = 4 * w + r;
        const float* g = yb + (size_t)row * CTC_V + lane * 4;
        gld_lds16f(g, &rows[row][0]);
        gld_lds16f(g + 256, &rows[row][256]);
    }
    asm volatile("s_waitcnt vmcnt(0)" ::: "memory");

#pragma unroll
    for (int r = 0; r < 4; ++r) {
        const int row = 4 * w + r;
        const float* rowp = &rows[row][0];
        const float c0 = rowp[lp.x] + EPSF;
        const float c1 = rowp[lp.y] + EPSF;
        const uint32_t pk = rne16(c0) | (rne16(c1) << 16);
        pairs[((size_t)b * CTC_T + t0 + row) * 64 + lane] = pk;
        if (lane == 0) blk[b * CTC_T + t0 + row] = rowp[BLANK] + EPSF;
    }
}

// ---------------- K2: single-wave register-pipelined scan ----------------
__global__ __launch_bounds__(64, 1)
void ctc_scan2(const int* __restrict__ y_true,
               const uint32_t* __restrict__ pairs,
               const float* __restrict__ blk,
               float* __restrict__ out) {
    const int b = blockIdx.x;
    const int lane = threadIdx.x;

    const uint32_t* pcur = pairs + (size_t)b * CTC_T * 64 + lane;
    const float* bcur = blk + (size_t)b * CTC_T;

    const int labA = y_true[b * CTC_L + 2 * lane];
    const int labB = y_true[b * CTC_L + 2 * lane + 1];
    const int labPrev = __shfl_up(labB, 1);
    const float msk1 = (labA != labPrev) ? 1.0f : 0.0f;
    const float msk3 = (labB != labA) ? 1.0f : 0.0f;

    // pre-state: virtual "alpha[-1]" delta; t=0 becomes a uniform step
    float a0 = (lane == 0) ? 1.0f : 0.0f;
    float a1 = 0.0f, a2 = 0.0f, a3 = 0.0f, a4 = 0.0f;
    float curScale = 1.0f;
    int curE = 0, Eacc = 0;

    // 16-slot pair ring + double-buffered blank quads
    uint32_t v0, v1, v2, v3, v4, v5, v6, v7, v8, v9, v10, v11, v12, v13, v14, v15;
    float4 bqA0, bqA1, bqA2, bqA3, bqB0, bqB1, bqB2, bqB3;

    // prologue: slots t=0..15, blanks t=0..31
    v0  = pcur[0 * 64];  v1  = pcur[1 * 64];  v2  = pcur[2 * 64];  v3  = pcur[3 * 64];
    v4  = pcur[4 * 64];  v5  = pcur[5 * 64];  v6  = pcur[6 * 64];  v7  = pcur[7 * 64];
    v8  = pcur[8 * 64];  v9  = pcur[9 * 64];  v10 = pcur[10 * 64]; v11 = pcur[11 * 64];
    v12 = pcur[12 * 64]; v13 = pcur[13 * 64]; v14 = pcur[14 * 64]; v15 = pcur[15 * 64];
    bqA0 = *(const float4*)(bcur + 0);  bqA1 = *(const float4*)(bcur + 4);
    bqA2 = *(const float4*)(bcur + 8);  bqA3 = *(const float4*)(bcur + 12);
    bqB0 = *(const float4*)(bcur + 16); bqB1 = *(const float4*)(bcur + 20);
    bqB2 = *(const float4*)(bcur + 24); bqB3 = *(const float4*)(bcur + 28);

#define STEP(vk, bv) do {                                                  \
        const float pb_ = (bv);                                            \
        const float pA_ = __uint_as_float((vk) << 16);                     \
        const float pB_ = __uint_as_float((vk) & 0xffff0000u);             \
        const float pm1_ = dpp_mov0<0x138>(a3); /* wave_shr:1, lane0->0 */ \
        const float n0_ = (a0 + pm1_) * pb_;                               \
        const float n1_ = fmaf(msk1, pm1_, a0 + a1) * pA_;                 \
        const float n2_ = (a1 + a2) * pb_;                                 \
        const float n3_ = fmaf(msk3, a1, a2 + a3) * pB_;                   \
        const float n4_ = (a3 + a4) * pb_;                                 \
        a0 = n0_; a1 = n1_; a2 = n2_; a3 = n3_; a4 = n4_;                  \
    } while (0)

#define DORN() do {                                                        \
        a0 *= curScale; a1 *= curScale; a2 *= curScale;                    \
        a3 *= curScale; a4 *= curScale;                                    \
        Eacc += curE;                                                      \
        float m_ = fmaxf(fmaxf(fmaxf(a0, a1), fmaxf(a2, a3)), a4);         \
        m_ = dpp_max<0x111>(m_);  /* row_shr:1  */                         \
        m_ = dpp_max<0x112>(m_);  /* row_shr:2  */                         \
        m_ = dpp_max<0x114>(m_);  /* row_shr:4  */                         \
        m_ = dpp_max<0x118>(m_);  /* row_shr:8  */                         \
        m_ = dpp_max<0x142>(m_);  /* row_bcast:15 */                       \
        m_ = dpp_max<0x143>(m_);  /* row_bcast:31 */                       \
        const int mb_ = __builtin_amdgcn_readlane(__float_as_int(m_), 63); \
        const int e_ = (mb_ >> 23) & 255;                                  \
        int k_ = 127 + BIASE + 127 - e_;                                   \
        k_ = k_ > 254 ? 254 : (k_ < 1 ? 1 : k_);                           \
        curScale = __int_as_float((unsigned)k_ << 23);                     \
        curE = 127 - k_;                                                   \
    } while (0)

#define RELOAD(K) v##K = pcur[(16 + K) * 64]

    for (int ob = 0; ob < 32; ++ob) {
        // -------- phase A: t = 32*ob .. +15, blanks bqA --------
        STEP(v0,  bqA0.x); RELOAD(0);
        STEP(v1,  bqA0.y); RELOAD(1);
        STEP(v2,  bqA0.z); RELOAD(2);
        STEP(v3,  bqA0.w); RELOAD(3);  bqA0 = *(const float4*)(bcur + 32); DORN();
        STEP(v4,  bqA1.x); RELOAD(4);
        STEP(v5,  bqA1.y); RELOAD(5);
        STEP(v6,  bqA1.z); RELOAD(6);
        STEP(v7,  bqA1.w); RELOAD(7);  bqA1 = *(const float4*)(bcur + 36); DORN();
        STEP(v8,  bqA2.x); RELOAD(8);
        STEP(v9,  bqA2.y); RELOAD(9);
        STEP(v10, bqA2.z); RELOAD(10);
        STEP(v11, bqA2.w); RELOAD(11); bqA2 = *(const float4*)(bcur + 40); DORN();
        STEP(v12, bqA3.x); RELOAD(12);
        STEP(v13, bqA3.y); RELOAD(13);
        STEP(v14, bqA3.z); RELOAD(14);
        STEP(v15, bqA3.w); RELOAD(15); bqA3 = *(const float4*)(bcur + 44); DORN();
        pcur += 16 * 64;
        // -------- phase B: t = 32*ob+16 .. +31, blanks bqB --------
        STEP(v0,  bqB0.x); RELOAD(0);
        STEP(v1,  bqB0.y); RELOAD(1);
        STEP(v2,  bqB0.z); RELOAD(2);
        STEP(v3,  bqB0.w); RELOAD(3);  bqB0 = *(const float4*)(bcur + 48); DORN();
        STEP(v4,  bqB1.x); RELOAD(4);
        STEP(v5,  bqB1.y); RELOAD(5);
        STEP(v6,  bqB1.z); RELOAD(6);
        STEP(v7,  bqB1.w); RELOAD(7);  bqB1 = *(const float4*)(bcur + 52); DORN();
        STEP(v8,  bqB2.x); RELOAD(8);
        STEP(v9,  bqB2.y); RELOAD(9);
        STEP(v10, bqB2.z); RELOAD(10);
        STEP(v11, bqB2.w); RELOAD(11); bqB2 = *(const float4*)(bcur + 56); DORN();
        STEP(v12, bqB3.x); RELOAD(12);
        STEP(v13, bqB3.y); RELOAD(13);
        STEP(v14, bqB3.z); RELOAD(14);
        STEP(v15, bqB3.w); RELOAD(15); bqB3 = *(const float4*)(bcur + 60); DORN();
        pcur += 16 * 64;
        bcur += 32;
    }

    if (lane == 63) {
        out[b] = -(logf(a3 + a4) + (float)Eacc * LN2F);
    }
#undef RELOAD
#undef DORN
#undef STEP
}

// ---------------- fallback: round-5 single kernel ----------------
#define F_CHUNK 16
#define F_NBUF  4
#define F_NCH   (CTC_T / F_CHUNK)

__global__ __launch_bounds__(256, 1)
void ctc_fwd_stream(const int* __restrict__ y_true,
                    const float* __restrict__ y_pred,
                    float* __restrict__ out) {
    __shared__ __align__(16) float rows[F_NBUF][F_CHUNK][CTC_V];
    const int b = blockIdx.x;
    const int tid = threadIdx.x;
    const int wave = tid >> 6;
    const int lane = tid & 63;
    const float* __restrict__ yb = y_pred + (size_t)b * CTC_T * CTC_V;

    if (wave != 0) {
        const int w = wave - 1;
#define FISSUE(c_) do {                                                    \
            const int t0_ = (c_) * F_CHUNK;                                \
            float* bufb_ = &rows[(c_) & (F_NBUF - 1)][0][0];               \
            for (int l_ = w; l_ < F_CHUNK; l_ += 3) {                      \
                const float* g_ = yb + (size_t)(t0_ + l_) * CTC_V + lane * 4; \
                float* d_ = bufb_ + l_ * CTC_V;                            \
                gld_lds16f(g_, d_);                                        \
                gld_lds16f(g_ + 256, d_ + 256);                            \
            }                                                              \
        } while (0)
        FISSUE(0); FISSUE(1); FISSUE(2);
        if (w == 0) asm volatile("s_waitcnt vmcnt(24)" ::: "memory");
        else        asm volatile("s_waitcnt vmcnt(20)" ::: "memory");
        __builtin_amdgcn_s_barrier();
        __builtin_amdgcn_sched_barrier(0);
        for (int c = 0; c < F_NCH; ++c) {
            if (c + 3 < F_NCH) FISSUE(c + 3);
            if (c <= F_NCH - 4) {
                if (w == 0) asm volatile("s_waitcnt vmcnt(24)" ::: "memory");
                else        asm volatile("s_waitcnt vmcnt(20)" ::: "memory");
            } else if (c == F_NCH - 3) {
                if (w == 0) asm volatile("s_waitcnt vmcnt(12)" ::: "memory");
                else        asm volatile("s_waitcnt vmcnt(10)" ::: "memory");
            } else if (c == F_NCH - 2) {
                asm volatile("s_waitcnt vmcnt(0)" ::: "memory");
            }
            __builtin_amdgcn_s_barrier();
            __builtin_amdgcn_sched_barrier(0);
        }
        return;
#undef FISSUE
    }

    const int labA = y_true[b * CTC_L + 2 * lane];
    const int labB = y_true[b * CTC_L + 2 * lane + 1];
    const int labPrev = __shfl_up(labB, 1);
    const float msk1 = (labA != labPrev) ? 1.0f : 0.0f;
    const float msk3 = (labB != labA) ? 1.0f : 0.0f;

    float a0 = 0.0f, a1 = 0.0f, a2 = 0.0f, a3 = 0.0f, a4 = 0.0f;
    float curScale = 1.0f;
    int curE = 0, Eacc = 0;
    float pAA0, pBA0, blA0, pAA1, pBA1, blA1, pAA2, pBA2, blA2, pAA3, pBA3, blA3;
    float pAB0, pBB0, blB0, pAB1, pBB1, blB1, pAB2, pBB2, blB2, pAB3, pBB3, blB3;
    float pAC0, pBC0, blC0, pAC1, pBC1, blC1, pAC2, pBC2, blC2, pAC3, pBC3, blC3;

#define FLOADG(S, l_) do {                                                 \
        const float* r0_ = bufc + ((l_) + 0) * CTC_V;                      \
        const float* r1_ = bufc + ((l_) + 1) * CTC_V;                      \
        const float* r2_ = bufc + ((l_) + 2) * CTC_V;                      \
        const float* r3_ = bufc + ((l_) + 3) * CTC_V;                      \
        pA##S##0 = r0_[labA]; pB##S##0 = r0_[labB]; bl##S##0 = r0_[BLANK]; \
        pA##S##1 = r1_[labA]; pB##S##1 = r1_[labB]; bl##S##1 = r1_[BLANK]; \
        pA##S##2 = r2_[labA]; pB##S##2 = r2_[labB]; bl##S##2 = r2_[BLANK]; \
        pA##S##3 = r3_[labA]; pB##S##3 = r3_[labB]; bl##S##3 = r3_[BLANK]; \
    } while (0)
#define FDOSTEP(S, k) do {                                                 \
        const float pb_ = bl##S##k + EPSF;                                 \
        const float pA_ = pA##S##k + EPSF;                                 \
        const float pB_ = pB##S##k + EPSF;                                 \
        const float pm1_ = dpp_mov0<0x138>(a3);                            \
        const float n0_ = (a0 + pm1_) * pb_;                               \
        const float n1_ = fmaf(msk1, pm1_, a0 + a1) * pA_;                 \
        const float n2_ = (a1 + a2) * pb_;                                 \
        const float n3_ = fmaf(msk3, a1, a2 + a3) * pB_;                   \
        const float n4_ = (a3 + a4) * pb_;                                 \
        a0 = n0_; a1 = n1_; a2 = n2_; a3 = n3_; a4 = n4_;                  \
    } while (0)
#define FDORN() do {                                                       \
        a0 *= curScale; a1 *= curScale; a2 *= curScale;                    \
        a3 *= curScale; a4 *= curScale;                                    \
        Eacc += curE;                                                      \
        float m_ = fmaxf(fmaxf(fmaxf(a0, a1), fmaxf(a2, a3)), a4);         \
        m_ = dpp_max<0x111>(m_); m_ = dpp_max<0x112>(m_);                  \
        m_ = dpp_max<0x114>(m_); m_ = dpp_max<0x118>(m_);                  \
        m_ = dpp_max<0x142>(m_); m_ = dpp_max<0x143>(m_);                  \
        const int mb_ = __builtin_amdgcn_readlane(__float_as_int(m_), 63); \
        const int e_ = (mb_ >> 23) & 255;                                  \
        int k_ = 127 + BIASE + 127 - e_;                                   \
        k_ = k_ > 254 ? 254 : (k_ < 1 ? 1 : k_);                           \
        curScale = __int_as_float((unsigned)k_ << 23);                     \
        curE = 127 - k_;                                                   \
    } while (0)
#define FPROC4_RN(S) do {                                                  \
        FDOSTEP(S, 0); FDORN();                                            \
        FDOSTEP(S, 1); FDOSTEP(S, 2); FDOSTEP(S, 3);                       \
    } while (0)

    __builtin_amdgcn_s_barrier();
    __builtin_amdgcn_sched_barrier(0);
    for (int c = 0; c < F_NCH; ++c) {
        const float* bufc = &rows[c & (F_NBUF - 1)][0][0];
        if (c == 0) {
            const float pb0 = bufc[BLANK] + EPSF;
            const float plA = bufc[labA] + EPSF;
            FLOADG(A, 0); FLOADG(B, 4); FLOADG(C, 8);
            a0 = (lane == 0) ? pb0 : 0.0f;
            a1 = (lane == 0) ? plA : 0.0f;
            FDOSTEP(A, 1); FDOSTEP(A, 2); FDOSTEP(A, 3);
            FLOADG(A, 12);
            FPROC4_RN(B); FPROC4_RN(C); FPROC4_RN(A);
        } else {
            FLOADG(A, 0); FLOADG(B, 4); FLOADG(C, 8);
            FPROC4_RN(A); FLOADG(A, 12);
            FPROC4_RN(B); FPROC4_RN(C); FPROC4_RN(A);
        }
        __builtin_amdgcn_s_barrier();
        __builtin_amdgcn_sched_barrier(0);
    }
    if (lane == 63) {
        out[b] = -(logf(a3 + a4) + (float)Eacc * LN2F);
    }
#undef FPROC4_RN
#undef FDORN
#undef FDOSTEP
#undef FLOADG
}

extern "C" void kernel_launch(void* const* d_in, const int* in_sizes, int n_in,
                              void* d_out, int out_size, void* d_ws, size_t ws_size,
                              hipStream_t stream) {
    (void)in_sizes; (void)n_in; (void)out_size;
    const int* y_true = (const int*)d_in[0];     // [B, L] int32
    const float* y_pred = (const float*)d_in[1]; // [B, T, V] float32
    float* out = (float*)d_out;                  // [B, 1] float32

    const size_t pairsBytes = (size_t)CTC_B * CTC_T * 64 * sizeof(uint32_t); // 16.78 MB
    const size_t blkBytes = (size_t)CTC_B * CTC_T * sizeof(float);           // 256 KB
    const size_t need = pairsBytes + blkBytes + 65536;                       // + overread slack
    if (ws_size >= need) {
        uint32_t* pairs = (uint32_t*)d_ws;
        float* blk = (float*)((char*)d_ws + pairsBytes);
        ctc_gather<<<CTC_B * (CTC_T / K1ROWS), 256, 0, stream>>>(y_true, y_pred, pairs, blk);
        ctc_scan2<<<CTC_B, 64, 0, stream>>>(y_true, pairs, blk, out);
    } else {
        ctc_fwd_stream<<<CTC_B, 256, 0, stream>>>(y_true, y_pred, out);
    }
}

// Round 10
// 78.749 us; speedup vs baseline: 1.2088x; 1.1970x over previous
//
#include <hip/hip_runtime.h>
#include <hip/hip_bf16.h>
#include <cstdint>

// CTC forward loss (keras ctc_batch_cost), B=64 T=1024 L=128 V=512.
// Two-phase:
//   K1 (gather, 4096 blocks): y_pred rows -> LDS -> gather 129 probs/(b,t),
//      pre-add EPSF, bf16-pack label pairs. Output is GROUP-TRANSPOSED:
//      pairs[(b*T+t)/4][lane][4] u32  (lane's 4 consecutive steps contiguous,
//      lanes adjacent -> K2 reads 4 steps per coalesced dwordx4);
//      blanks as f32x4 per group in blk[B*T].
//   K2 (scan, 64 blocks x 1 wave): register-pipelined scan with ASM loads.
//      r9 post-mortem: VGPR=40 proved hipcc sank the HIP-level prefetch ring
//      (each step then stalls ~180cy on L2/L3). Fix: asm volatile
//      global_load_dwordx4 into named ext-vector regs + counted vmcnt(16) +
//      sched_barrier(0) (rule #18) — pipeline is structurally un-sinkable.
//      32-step phases, depth-1 (issue p+1 at start of p ~= 1200cy lead).
//      DPP cross-lane; renorm every 4 steps, deferred, BIASE 90 (r9 numerics).
// Fallback to round-5 single kernel if ws too small.

#define CTC_B 64
#define CTC_T 1024
#define CTC_L 128
#define CTC_V 512
#define BLANK (CTC_V - 1)
#define EPSF 1e-7f
#define LN2F 0.69314718055994530942f
#define BIASE 90
#define K1ROWS 16

typedef __attribute__((ext_vector_type(4))) unsigned int u32x4;
typedef __attribute__((ext_vector_type(4))) float f32x4;

__device__ __forceinline__ void gld_lds16f(const float* g, float* l) {
    __builtin_amdgcn_global_load_lds(
        (const __attribute__((address_space(1))) unsigned int*)g,
        (__attribute__((address_space(3))) unsigned int*)l, 16, 0, 0);
}

template<int CTRL>
__device__ __forceinline__ float dpp_mov0(float v) {
    int r = __builtin_amdgcn_update_dpp(0, __float_as_int(v), CTRL, 0xf, 0xf, false);
    return __int_as_float(r);
}
template<int CTRL>
__device__ __forceinline__ float dpp_max(float v) {
    int r = __builtin_amdgcn_update_dpp(__float_as_int(v), __float_as_int(v),
                                        CTRL, 0xf, 0xf, false);
    return fmaxf(v, __int_as_float(r));
}
__device__ __forceinline__ uint32_t rne16(float x) {
    return (__float_as_uint(x) + 0x8000u) >> 16;
}

// ---------------- K1: gather + pack, group-transposed output ----------------
__global__ __launch_bounds__(256, 1)
void ctc_gather(const int* __restrict__ y_true,
                const float* __restrict__ y_pred,
                uint32_t* __restrict__ pairs,
                float* __restrict__ blk) {
    __shared__ __align__(16) float rows[K1ROWS][CTC_V];   // 32 KB

    const int bid = blockIdx.x;
    const int b = bid >> 6;
    const int t0 = (bid & 63) * K1ROWS;
    const int w = threadIdx.x >> 6;       // wave owns rows 4w..4w+3 = one group
    const int lane = threadIdx.x & 63;
    const float* __restrict__ yb = y_pred + ((size_t)b * CTC_T + t0) * CTC_V;

    const int2 lp = *(const int2*)&y_true[b * CTC_L + 2 * lane];

#pragma unroll
    for (int r = 0; r < 4; ++r) {
        const int row = 4 * w + r;
        const float* g = yb + (size_t)row * CTC_V + lane * 4;
        gld_lds16f(g, &rows[row][0]);
        gld_lds16f(g + 256, &rows[row][256]);
    }
    asm volatile("s_waitcnt vmcnt(0)" ::: "memory");

    uint32_t pk0, pk1, pk2, pk3;
    float bl0, bl1, bl2, bl3;
#define PACKROW(R) do {                                                    \
        const float* rowp = &rows[4 * w + (R)][0];                         \
        pk##R = rne16(rowp[lp.x] + EPSF) | (rne16(rowp[lp.y] + EPSF) << 16); \
        bl##R = rowp[BLANK] + EPSF;                                        \
    } while (0)
    PACKROW(0); PACKROW(1); PACKROW(2); PACKROW(3);
#undef PACKROW

    const size_t gidx = ((size_t)b * CTC_T + t0) / 4 + w;  // global group index
    u32x4 pv; pv.x = pk0; pv.y = pk1; pv.z = pk2; pv.w = pk3;
    ((u32x4*)pairs)[gidx * 64 + lane] = pv;                 // coalesced 1KB/wave
    if (lane == 0) {
        f32x4 bv; bv.x = bl0; bv.y = bl1; bv.z = bl2; bv.w = bl3;
        ((f32x4*)blk)[gidx] = bv;
    }
}

// ---------------- K2: asm-pipelined single-wave scan ----------------
#define GLD4U(dst, addr, OFF)                                              \
    asm volatile("global_load_dwordx4 %0, %1, off offset:" OFF             \
                 : "=v"(dst) : "v"(addr) : "memory")
#define GLD4F(dst, addr, OFF)                                              \
    asm volatile("global_load_dwordx4 %0, %1, off offset:" OFF             \
                 : "=v"(dst) : "v"(addr) : "memory")

__global__ __launch_bounds__(64, 1)
void ctc_scan3(const int* __restrict__ y_true,
               const uint32_t* __restrict__ pairs,
               const float* __restrict__ blk,
               float* __restrict__ out) {
    const int b = blockIdx.x;
    const int lane = threadIdx.x;

    // per-lane pair base: group stride 1024B, 256 groups per batch row
    const uint8_t* pbase = (const uint8_t*)pairs + (size_t)b * 262144 + (size_t)lane * 16;
    const uint8_t* bbase = (const uint8_t*)blk + (size_t)b * 4096;  // wave-uniform

    const int labA = y_true[b * CTC_L + 2 * lane];
    const int labB = y_true[b * CTC_L + 2 * lane + 1];
    const int labPrev = __shfl_up(labB, 1);
    const float msk1 = (labA != labPrev) ? 1.0f : 0.0f;
    const float msk3 = (labB != labA) ? 1.0f : 0.0f;

    // pre-state: virtual "alpha[-1]" delta; t=0 is a uniform step
    float a0 = (lane == 0) ? 1.0f : 0.0f;
    float a1 = 0.0f, a2 = 0.0f, a3 = 0.0f, a4 = 0.0f;
    float curScale = 1.0f;
    int curE = 0, Eacc = 0;

    // two named register sets: 8 pair-quads + 8 blank-quads each
    u32x4 PA0, PA1, PA2, PA3, PA4, PA5, PA6, PA7;
    f32x4 QA0, QA1, QA2, QA3, QA4, QA5, QA6, QA7;
    u32x4 PB0, PB1, PB2, PB3, PB4, PB5, PB6, PB7;
    f32x4 QB0, QB1, QB2, QB3, QB4, QB5, QB6, QB7;

#define ISSUE_PHASE(S) do {                                                \
        const uint8_t* ph_ = pbase + 4096;                                 \
        GLD4U(P##S##0, pbase, "0");    GLD4U(P##S##1, pbase, "1024");      \
        GLD4U(P##S##2, pbase, "2048"); GLD4U(P##S##3, pbase, "3072");      \
        GLD4U(P##S##4, ph_,   "0");    GLD4U(P##S##5, ph_,   "1024");      \
        GLD4U(P##S##6, ph_,   "2048"); GLD4U(P##S##7, ph_,   "3072");      \
        GLD4F(Q##S##0, bbase, "0");    GLD4F(Q##S##1, bbase, "16");        \
        GLD4F(Q##S##2, bbase, "32");   GLD4F(Q##S##3, bbase, "48");        \
        GLD4F(Q##S##4, bbase, "64");   GLD4F(Q##S##5, bbase, "80");        \
        GLD4F(Q##S##6, bbase, "96");   GLD4F(Q##S##7, bbase, "112");       \
        pbase += 8192; bbase += 128;                                       \
    } while (0)

#define WAITP() do {                                                       \
        asm volatile("s_waitcnt vmcnt(16)" ::: "memory");                  \
        __builtin_amdgcn_sched_barrier(0);                                 \
    } while (0)

#define STEP(vk, bv) do {                                                  \
        const float pb_ = (bv);                                            \
        const float pA_ = __uint_as_float((vk) << 16);                     \
        const float pB_ = __uint_as_float((vk) & 0xffff0000u);             \
        const float pm1_ = dpp_mov0<0x138>(a3); /* wave_shr:1, lane0->0 */ \
        const float n0_ = (a0 + pm1_) * pb_;                               \
        const float n1_ = fmaf(msk1, pm1_, a0 + a1) * pA_;                 \
        const float n2_ = (a1 + a2) * pb_;                                 \
        const float n3_ = fmaf(msk3, a1, a2 + a3) * pB_;                   \
        const float n4_ = (a3 + a4) * pb_;                                 \
        a0 = n0_; a1 = n1_; a2 = n2_; a3 = n3_; a4 = n4_;                  \
    } while (0)

#define DORN() do {                                                        \
        a0 *= curScale; a1 *= curScale; a2 *= curScale;                    \
        a3 *= curScale; a4 *= curScale;                                    \
        Eacc += curE;                                                      \
        float m_ = fmaxf(fmaxf(fmaxf(a0, a1), fmaxf(a2, a3)), a4);         \
        m_ = dpp_max<0x111>(m_);  /* row_shr:1  */                         \
        m_ = dpp_max<0x112>(m_);  /* row_shr:2  */                         \
        m_ = dpp_max<0x114>(m_);  /* row_shr:4  */                         \
        m_ = dpp_max<0x118>(m_);  /* row_shr:8  */                         \
        m_ = dpp_max<0x142>(m_);  /* row_bcast:15 */                       \
        m_ = dpp_max<0x143>(m_);  /* row_bcast:31 */                       \
        const int mb_ = __builtin_amdgcn_readlane(__float_as_int(m_), 63); \
        const int e_ = (mb_ >> 23) & 255;                                  \
        int k_ = 127 + BIASE + 127 - e_;                                   \
        k_ = k_ > 254 ? 254 : (k_ < 1 ? 1 : k_);                           \
        curScale = __int_as_float((unsigned)k_ << 23);                     \
        curE = 127 - k_;                                                   \
    } while (0)

#define GROUPSTEP(S, G) do {                                               \
        STEP(P##S##G.x, Q##S##G.x);                                        \
        STEP(P##S##G.y, Q##S##G.y);                                        \
        STEP(P##S##G.z, Q##S##G.z);                                        \
        STEP(P##S##G.w, Q##S##G.w);                                        \
        DORN();                                                            \
    } while (0)

#define PROC_PHASE(S) do {                                                 \
        GROUPSTEP(S, 0); GROUPSTEP(S, 1); GROUPSTEP(S, 2); GROUPSTEP(S, 3);\
        GROUPSTEP(S, 4); GROUPSTEP(S, 5); GROUPSTEP(S, 6); GROUPSTEP(S, 7);\
    } while (0)

    ISSUE_PHASE(A);                 // phase 0
    for (int it = 0; it < 16; ++it) {
        ISSUE_PHASE(B);             // phase 2it+1
        WAITP();                    // phase 2it (A) ready
        PROC_PHASE(A);
        ISSUE_PHASE(A);             // phase 2it+2 (last iter: slack overread, unused)
        WAITP();                    // phase 2it+1 (B) ready
        PROC_PHASE(B);
    }

    if (lane == 63) {
        out[b] = -(logf(a3 + a4) + (float)Eacc * LN2F);
    }
#undef PROC_PHASE
#undef GROUPSTEP
#undef DORN
#undef STEP
#undef WAITP
#undef ISSUE_PHASE
}
#undef GLD4U
#undef GLD4F

// ---------------- fallback: round-5 single kernel ----------------
#define F_CHUNK 16
#define F_NBUF  4
#define F_NCH   (CTC_T / F_CHUNK)

__global__ __launch_bounds__(256, 1)
void ctc_fwd_stream(const int* __restrict__ y_true,
                    const float* __restrict__ y_pred,
                    float* __restrict__ out) {
    __shared__ __align__(16) float rows[F_NBUF][F_CHUNK][CTC_V];
    const int b = blockIdx.x;
    const int tid = threadIdx.x;
    const int wave = tid >> 6;
    const int lane = tid & 63;
    const float* __restrict__ yb = y_pred + (size_t)b * CTC_T * CTC_V;

    if (wave != 0) {
        const int w = wave - 1;
#define FISSUE(c_) do {                                                    \
            const int t0_ = (c_) * F_CHUNK;                                \
            float* bufb_ = &rows[(c_) & (F_NBUF - 1)][0][0];               \
            for (int l_ = w; l_ < F_CHUNK; l_ += 3) {                      \
                const float* g_ = yb + (size_t)(t0_ + l_) * CTC_V + lane * 4; \
                float* d_ = bufb_ + l_ * CTC_V;                            \
                gld_lds16f(g_, d_);                                        \
                gld_lds16f(g_ + 256, d_ + 256);                            \
            }                                                              \
        } while (0)
        FISSUE(0); FISSUE(1); FISSUE(2);
        if (w == 0) asm volatile("s_waitcnt vmcnt(24)" ::: "memory");
        else        asm volatile("s_waitcnt vmcnt(20)" ::: "memory");
        __builtin_amdgcn_s_barrier();
        __builtin_amdgcn_sched_barrier(0);
        for (int c = 0; c < F_NCH; ++c) {
            if (c + 3 < F_NCH) FISSUE(c + 3);
            if (c <= F_NCH - 4) {
                if (w == 0) asm volatile("s_waitcnt vmcnt(24)" ::: "memory");
                else        asm volatile("s_waitcnt vmcnt(20)" ::: "memory");
            } else if (c == F_NCH - 3) {
                if (w == 0) asm volatile("s_waitcnt vmcnt(12)" ::: "memory");
                else        asm volatile("s_waitcnt vmcnt(10)" ::: "memory");
            } else if (c == F_NCH - 2) {
                asm volatile("s_waitcnt vmcnt(0)" ::: "memory");
            }
            __builtin_amdgcn_s_barrier();
            __builtin_amdgcn_sched_barrier(0);
        }
        return;
#undef FISSUE
    }

    const int labA = y_true[b * CTC_L + 2 * lane];
    const int labB = y_true[b * CTC_L + 2 * lane + 1];
    const int labPrev = __shfl_up(labB, 1);
    const float msk1 = (labA != labPrev) ? 1.0f : 0.0f;
    const float msk3 = (labB != labA) ? 1.0f : 0.0f;

    float a0 = 0.0f, a1 = 0.0f, a2 = 0.0f, a3 = 0.0f, a4 = 0.0f;
    float curScale = 1.0f;
    int curE = 0, Eacc = 0;
    float pAA0, pBA0, blA0, pAA1, pBA1, blA1, pAA2, pBA2, blA2, pAA3, pBA3, blA3;
    float pAB0, pBB0, blB0, pAB1, pBB1, blB1, pAB2, pBB2, blB2, pAB3, pBB3, blB3;
    float pAC0, pBC0, blC0, pAC1, pBC1, blC1, pAC2, pBC2, blC2, pAC3, pBC3, blC3;

#define FLOADG(S, l_) do {                                                 \
        const float* r0_ = bufc + ((l_) + 0) * CTC_V;                      \
        const float* r1_ = bufc + ((l_) + 1) * CTC_V;                      \
        const float* r2_ = bufc + ((l_) + 2) * CTC_V;                      \
        const float* r3_ = bufc + ((l_) + 3) * CTC_V;                      \
        pA##S##0 = r0_[labA]; pB##S##0 = r0_[labB]; bl##S##0 = r0_[BLANK]; \
        pA##S##1 = r1_[labA]; pB##S##1 = r1_[labB]; bl##S##1 = r1_[BLANK]; \
        pA##S##2 = r2_[labA]; pB##S##2 = r2_[labB]; bl##S##2 = r2_[BLANK]; \
        pA##S##3 = r3_[labA]; pB##S##3 = r3_[labB]; bl##S##3 = r3_[BLANK]; \
    } while (0)
#define FDOSTEP(S, k) do {                                                 \
        const float pb_ = bl##S##k + EPSF;                                 \
        const float pA_ = pA##S##k + EPSF;                                 \
        const float pB_ = pB##S##k + EPSF;                                 \
        const float pm1_ = dpp_mov0<0x138>(a3);                            \
        const float n0_ = (a0 + pm1_) * pb_;                               \
        const float n1_ = fmaf(msk1, pm1_, a0 + a1) * pA_;                 \
        const float n2_ = (a1 + a2) * pb_;                                 \
        const float n3_ = fmaf(msk3, a1, a2 + a3) * pB_;                   \
        const float n4_ = (a3 + a4) * pb_;                                 \
        a0 = n0_; a1 = n1_; a2 = n2_; a3 = n3_; a4 = n4_;                  \
    } while (0)
#define FDORN() do {                                                       \
        a0 *= curScale; a1 *= curScale; a2 *= curScale;                    \
        a3 *= curScale; a4 *= curScale;                                    \
        Eacc += curE;                                                      \
        float m_ = fmaxf(fmaxf(fmaxf(a0, a1), fmaxf(a2, a3)), a4);         \
        m_ = dpp_max<0x111>(m_); m_ = dpp_max<0x112>(m_);                  \
        m_ = dpp_max<0x114>(m_); m_ = dpp_max<0x118>(m_);                  \
        m_ = dpp_max<0x142>(m_); m_ = dpp_max<0x143>(m_);                  \
        const int mb_ = __builtin_amdgcn_readlane(__float_as_int(m_), 63); \
        const int e_ = (mb_ >> 23) & 255;                                  \
        int k_ = 127 + BIASE + 127 - e_;                                   \
        k_ = k_ > 254 ? 254 : (k_ < 1 ? 1 : k_);                           \
        curScale = __int_as_float((unsigned)k_ << 23);                     \
        curE = 127 - k_;                                                   \
    } while (0)
#define FPROC4_RN(S) do {                                                  \
        FDOSTEP(S, 0); FDORN();                                            \
        FDOSTEP(S, 1); FDOSTEP(S, 2); FDOSTEP(S, 3);                       \
    } while (0)

    __builtin_amdgcn_s_barrier();
    __builtin_amdgcn_sched_barrier(0);
    for (int c = 0; c < F_NCH; ++c) {
        const float* bufc = &rows[c & (F_NBUF - 1)][0][0];
        if (c == 0) {
            const float pb0 = bufc[BLANK] + EPSF;
            const float plA = bufc[labA] + EPSF;
            FLOADG(A, 0); FLOADG(B, 4); FLOADG(C, 8);
            a0 = (lane == 0) ? pb0 : 0.0f;
            a1 = (lane == 0) ? plA : 0.0f;
            FDOSTEP(A, 1); FDOSTEP(A, 2); FDOSTEP(A, 3);
            FLOADG(A, 12);
            FPROC4_RN(B); FPROC4_RN(C); FPROC4_RN(A);
        } else {
            FLOADG(A, 0); FLOADG(B, 4); FLOADG(C, 8);
            FPROC4_RN(A); FLOADG(A, 12);
            FPROC4_RN(B); FPROC4_RN(C); FPROC4_RN(A);
        }
        __builtin_amdgcn_s_barrier();
        __builtin_amdgcn_sched_barrier(0);
    }
    if (lane == 63) {
        out[b] = -(logf(a3 + a4) + (float)Eacc * LN2F);
    }
#undef FPROC4_RN
#undef FDORN
#undef FDOSTEP
#undef FLOADG
}

extern "C" void kernel_launch(void* const* d_in, const int* in_sizes, int n_in,
                              void* d_out, int out_size, void* d_ws, size_t ws_size,
                              hipStream_t stream) {
    (void)in_sizes; (void)n_in; (void)out_size;
    const int* y_true = (const int*)d_in[0];     // [B, L] int32
    const float* y_pred = (const float*)d_in[1]; // [B, T, V] float32
    float* out = (float*)d_out;                  // [B, 1] float32

    const size_t pairsBytes = (size_t)CTC_B * CTC_T * 64 * sizeof(uint32_t); // 16.78 MB
    const size_t blkBytes = (size_t)CTC_B * CTC_T * sizeof(float);           // 256 KB
    const size_t need = pairsBytes + blkBytes + 65536;                       // + overread slack
    if (ws_size >= need) {
        uint32_t* pairs = (uint32_t*)d_ws;
        float* blk = (float*)((char*)d_ws + pairsBytes);
        ctc_gather<<<CTC_B * (CTC_T / K1ROWS), 256, 0, stream>>>(y_true, y_pred, pairs, blk);
        ctc_scan3<<<CTC_B, 64, 0, stream>>>(y_true, pairs, blk, out);
    } else {
        ctc_fwd_stream<<<CTC_B, 256, 0, stream>>>(y_true, y_pred, out);
    }
}